// Round 10
// baseline (223.146 us; speedup 1.0000x reference)
//
#include <hip/hip_runtime.h>
#include <hip/hip_bf16.h>
#include <math.h>

// Problem dims (fixed by reference)
#define BB 4
#define TT 1024
#define DD 1024
#define HPS 4          // heads per scale
#define C0 21
#define C1 41
#define N0 (HPS * C0)  // 84
#define N1 (HPS * C1)  // 164
#define NL 256         // padded combined logits width (84 + 164 = 248 -> 256)
#define BT (BB * TT)   // 4096
#define TB 64          // t-tile for window kernel
#define HALO 20
#define HB (TB + 2 * HALO)  // 104 rows staged
#define KSPLIT 2       // split-K for logits GEMM

typedef unsigned int uint;
typedef __bf16 bf16x8 __attribute__((ext_vector_type(8)));
typedef float f32x4 __attribute__((ext_vector_type(4)));

__device__ __forceinline__ ushort f2bf(float f) {
    union { float f; uint u; } v; v.f = f;
    uint u = v.u;
    uint r = (u + 0x7FFFu + ((u >> 16) & 1u)) >> 16;
    return (ushort)r;
}
__device__ __forceinline__ float bf2f(ushort s) {
    union { uint u; float f; } v; v.u = ((uint)s) << 16;
    return v.f;
}

// ---------------- fused conversion kernel ----------------
#define RQ  4096
#define R1  (RQ + 2048)
#define R2  (R1 + 1024)
#define R3  (R2 + 96)
#define R4  (R3 + 192)

__device__ __forceinline__ void transpose_tile(
    const float* __restrict__ in, ushort* __restrict__ out,
    int K, int Nin, int n_base, int Npad, int nx, int ky, int tid)
{
    __shared__ float tile[32][33];
    const int tx = tid & 31;
    const int ty = tid >> 5;   // 0..7
    const int n0 = nx * 32;
    const int k0 = ky * 32;
    #pragma unroll
    for (int i = 0; i < 4; i++) {
        int k = k0 + ty + i * 8;
        int n = n0 + tx;
        float v = (k < K && n < Nin) ? in[(size_t)k * Nin + n] : 0.0f;
        tile[ty + i * 8][tx] = v;
    }
    __syncthreads();
    #pragma unroll
    for (int i = 0; i < 4; i++) {
        int n = n0 + ty + i * 8;
        int k = k0 + tx;
        if (n < Npad && k < K)
            out[(size_t)(n_base + n) * K + k] = f2bf(tile[tx][ty + i * 8]);
    }
}

__global__ __launch_bounds__(256) void convert_all(
    const float* __restrict__ query, ushort* __restrict__ query_bf,
    const float* __restrict__ W_qv,  ushort* __restrict__ WqvT,
    const float* __restrict__ W_out, ushort* __restrict__ WoutT,
    const float* __restrict__ W2_0, const float* __restrict__ W2_1,
    ushort* __restrict__ W2T)
{
    const int blk = blockIdx.x;
    const int tid = threadIdx.x;
    if (blk < RQ) {
        int i = blk * 1024 + tid * 4;
        float4 v = *(const float4*)(query + i);
        ushort4 o;
        o.x = f2bf(v.x); o.y = f2bf(v.y); o.z = f2bf(v.z); o.w = f2bf(v.w);
        *(ushort4*)(query_bf + i) = o;
    } else if (blk < R1) {
        int idx = blk - RQ;                // 64 x 32
        transpose_tile(W_qv, WqvT, DD, 2 * DD, 0, 2 * DD, idx & 63, idx >> 6, tid);
    } else if (blk < R2) {
        int idx = blk - R1;                // 32 x 32
        transpose_tile(W_out, WoutT, DD, DD, 0, DD, idx & 31, idx >> 5, tid);
    } else if (blk < R3) {
        int idx = blk - R2;                // 3 x 32
        transpose_tile(W2_0, W2T, DD, N0, 0, N0, idx % 3, idx / 3, tid);
    } else {
        int idx = blk - R3;                // 6 x 32
        transpose_tile(W2_1, W2T, DD, N1, N0, NL - N0, idx % 6, idx / 6, tid);
    }
}

// ---- bf16 MFMA GEMM, 128x64 tile, BK=32, LDS double-buffer, 1 barrier/iter ----
// A: [M][K] bf16 row-major. Bt: [N][K] bf16 row-major.
// LDS per buffer: A [kblk 0..3][row 0..127][8], B [kblk 0..3][row 0..63][8]
// (k-major, zero-conflict reads AND writes — R9-measured).
// Pipeline per iter: ds_write next tile into buf^1 (regs prefetched last iter),
// issue loads for it+2, compute current buf, ONE barrier.
// XCD-banded swizzle: g -> xcd=g&7, ry=xcd*4+(s&3), cx=s>>2; per-XCD A band
// = 4 rows x 256 KB = 1 MB (fits 4 MB L2).  nY must be 32 (BT/128).
// MODE 0: Cf[row*ldc+col] = acc
// MODE 2: col<DD -> Cb = bf16(relu(acc)); else Cv = bf16(acc)
// MODE 3: Cf[(bz*BT + row)*ldc + col] = acc   (split-K partial)
template <int MODE>
__global__ __launch_bounds__(256) void gemm_db(
    const ushort* __restrict__ A, const ushort* __restrict__ Bt,
    int K, int klen,
    float* __restrict__ Cf, ushort* __restrict__ Cb, ushort* __restrict__ Cv,
    int ldc)
{
    __shared__ ushort As[2][4 * 128 * 8];   // 2 x 8 KB
    __shared__ ushort Bs[2][4 * 64 * 8];    // 2 x 4 KB (total 24 KB)

    const int tid = threadIdx.x;
    const int wv  = tid >> 6;         // wave 0..3
    const int ln  = tid & 63;
    // XCD-banded swizzle
    const int g   = blockIdx.x;
    const int xcd = g & 7;
    const int s   = g >> 3;
    const int ry  = xcd * 4 + (s & 3);   // 0..31
    const int cx  = s >> 2;
    const int row0 = ry * 128;
    const int col0 = cx * 64;
    const int kbase = blockIdx.y * klen;
    const int wr = wv * 32;           // wave row offset (M split across waves)
    const int l15 = ln & 15;
    const int lq  = ln >> 4;          // 0..3

    f32x4 acc[2][4];
    #pragma unroll
    for (int i = 0; i < 2; i++)
        #pragma unroll
        for (int j = 0; j < 4; j++)
            acc[i][j] = (f32x4){0.f, 0.f, 0.f, 0.f};

    // staging maps (zero-conflict ds_write_b128)
    const int srow = tid & 127;          // A row
    const int cp   = (tid >> 7) * 2;     // A chunk pair: 0 or 2
    const ushort* gA = A + (size_t)(row0 + srow) * K + kbase + cp * 8;
    const int awo0 = cp * 1024 + srow * 8;
    const int awo1 = awo0 + 1024;
    const int brow = tid & 63;           // B row
    const int bc   = tid >> 6;           // B chunk 0..3 (= wave id)
    const ushort* gB = Bt + (size_t)(col0 + brow) * K + kbase + bc * 8;
    const int bwo = bc * 512 + brow * 8;

    const int iters = klen >> 5;   // BK = 32

    // prologue: tile 0 -> buf 0
    {
        uint4 a0 = *(const uint4*)(gA);
        uint4 a1 = *(const uint4*)(gA + 8);
        uint4 b0 = *(const uint4*)(gB);
        *(uint4*)&As[0][awo0] = a0;
        *(uint4*)&As[0][awo1] = a1;
        *(uint4*)&Bs[0][bwo]  = b0;
    }
    // prefetch tile 1 into regs
    uint4 na0, na1, nb;
    if (iters > 1) {
        na0 = *(const uint4*)(gA + 32);
        na1 = *(const uint4*)(gA + 40);
        nb  = *(const uint4*)(gB + 32);
    }
    __syncthreads();

    for (int it = 0; it < iters; ++it) {
        const int buf = it & 1;
        // stage next tile into the other buffer (no hazard: its readers
        // finished before the previous barrier)
        if (it + 1 < iters) {
            *(uint4*)&As[buf ^ 1][awo0] = na0;
            *(uint4*)&As[buf ^ 1][awo1] = na1;
            *(uint4*)&Bs[buf ^ 1][bwo]  = nb;
        }
        // issue loads for tile it+2 (consumed next iteration)
        if (it + 2 < iters) {
            const int ko = (it + 2) * 32;
            na0 = *(const uint4*)(gA + ko);
            na1 = *(const uint4*)(gA + ko + 8);
            nb  = *(const uint4*)(gB + ko);
        }
        // compute current tile
        {
            bf16x8 af[2], bfr[4];
            #pragma unroll
            for (int mi = 0; mi < 2; mi++)
                af[mi] = *(const bf16x8*)&As[buf][lq * 1024 + (wr + mi * 16 + l15) * 8];
            #pragma unroll
            for (int ni = 0; ni < 4; ni++)
                bfr[ni] = *(const bf16x8*)&Bs[buf][lq * 512 + (ni * 16 + l15) * 8];
            #pragma unroll
            for (int mi = 0; mi < 2; mi++)
                #pragma unroll
                for (int ni = 0; ni < 4; ni++)
                    acc[mi][ni] = __builtin_amdgcn_mfma_f32_16x16x32_bf16(
                        af[mi], bfr[ni], acc[mi][ni], 0, 0, 0);
        }
        __syncthreads();   // the ONLY barrier per iteration
    }

    // Epilogue. D layout: col = lane&15, row = (lane>>4)*4 + reg.
    #pragma unroll
    for (int mi = 0; mi < 2; mi++) {
        #pragma unroll
        for (int ni = 0; ni < 4; ni++) {
            #pragma unroll
            for (int r = 0; r < 4; r++) {
                int row = row0 + wr + mi * 16 + lq * 4 + r;
                int col = col0 + ni * 16 + l15;
                float v = acc[mi][ni][r];
                if (MODE == 0) {
                    Cf[(size_t)row * ldc + col] = v;
                } else if (MODE == 2) {
                    if (col < DD) Cb[(size_t)row * DD + col] = f2bf(fmaxf(v, 0.0f));
                    else          Cv[(size_t)row * DD + (col - DD)] = f2bf(v);
                } else {
                    Cf[((size_t)blockIdx.y * BT + row) * ldc + col] = v;
                }
            }
        }
    }
}

// ------------- Tiled window kernel: block = (b, t-tile of 64, head) -------------
__global__ __launch_bounds__(256) void attn_window_kernel(
    const ushort* __restrict__ v,
    const float* __restrict__ Lp,
    const float* __restrict__ scale_w,
    ushort* __restrict__ x)
{
    const int blk = blockIdx.x;       // 256 blocks
    const int h  = blk & 3;
    const int tt = (blk >> 2) & 15;
    const int b  = blk >> 6;
    const int t0 = tt * TB;
    const int tid = threadIdx.x;
    const size_t PS = (size_t)BT * NL; // partial stride

    __shared__ ushort vs[HB][256];    // 53,248 B
    __shared__ float  cw[TB][42];

    const ushort* vb = v + (size_t)b * TT * DD + h * 256;
    #pragma unroll
    for (int i = 0; i < 13; i++) {
        int c = i * 256 + tid;
        int r = c >> 5;
        int cir = c & 31;
        int t = t0 - HALO + r;
        uint4 val = make_uint4(0, 0, 0, 0);
        if (t >= 0 && t < TT)
            val = *(const uint4*)(vb + (size_t)t * DD + cir * 8);
        *(uint4*)(&vs[r][cir * 8]) = val;
    }

    if (tid < TB) {
        const int bt = b * TT + t0 + tid;
        const float* Lb = Lp + (size_t)bt * NL;

        float s0 = scale_w[0], s1 = scale_w[1];
        float mm = fmaxf(s0, s1);
        float e0 = __expf(s0 - mm), e1 = __expf(s1 - mm);
        float inv01 = 1.0f / (e0 + e1);
        float sw0 = e0 * inv01, sw1 = e1 * inv01;

        float w0[C0], w1[C1];
        {
            const int off = h * C0;
            float m = -1e30f;
            #pragma unroll
            for (int j = 0; j < C0; j++) {
                w0[j] = Lb[off + j] + Lb[PS + off + j];
                m = fmaxf(m, w0[j]);
            }
            float s = 0.0f;
            #pragma unroll
            for (int j = 0; j < C0; j++) { w0[j] = __expf(w0[j] - m); s += w0[j]; }
            float inv = sw0 / s;
            #pragma unroll
            for (int j = 0; j < C0; j++) w0[j] *= inv;
        }
        {
            const int off = N0 + h * C1;
            float m = -1e30f;
            #pragma unroll
            for (int j = 0; j < C1; j++) {
                w1[j] = Lb[off + j] + Lb[PS + off + j];
                m = fmaxf(m, w1[j]);
            }
            float s = 0.0f;
            #pragma unroll
            for (int j = 0; j < C1; j++) { w1[j] = __expf(w1[j] - m); s += w1[j]; }
            float inv = sw1 / s;
            #pragma unroll
            for (int j = 0; j < C1; j++) w1[j] *= inv;
        }
        #pragma unroll
        for (int o = 0; o < C1; o++) {
            float w = w1[o];
            if (o >= 10 && o <= 30) w += w0[o - 10];
            cw[tid][o] = w;
        }
    }
    __syncthreads();

    const int tq = tid >> 6;
    const int dg = tid & 63;
    const int d  = dg * 4;

    for (int tloc = 0; tloc < 16; tloc++) {
        const int tp = tq * 16 + tloc;
        f32x4 acc = {0.f, 0.f, 0.f, 0.f};
        #pragma unroll
        for (int o = 0; o < C1; o++) {
            float w = cw[tp][o];
            ushort4 vv = *(const ushort4*)(&vs[tp + o][d]);
            acc[0] = fmaf(w, bf2f(vv.x), acc[0]);
            acc[1] = fmaf(w, bf2f(vv.y), acc[1]);
            acc[2] = fmaf(w, bf2f(vv.z), acc[2]);
            acc[3] = fmaf(w, bf2f(vv.w), acc[3]);
        }
        const int bt = b * TT + t0 + tp;
        ushort4 o4;
        o4.x = f2bf(acc[0]); o4.y = f2bf(acc[1]);
        o4.z = f2bf(acc[2]); o4.w = f2bf(acc[3]);
        *(ushort4*)(x + (size_t)bt * DD + h * 256 + d) = o4;
    }
}

// ---------------------------------- launch ----------------------------------
extern "C" void kernel_launch(void* const* d_in, const int* in_sizes, int n_in,
                              void* d_out, int out_size, void* d_ws, size_t ws_size,
                              hipStream_t stream)
{
    const float* query   = (const float*)d_in[0];
    const float* W_qv    = (const float*)d_in[3];
    const float* W2_0    = (const float*)d_in[4];
    const float* W2_1    = (const float*)d_in[5];
    const float* scale_w = (const float*)d_in[6];
    const float* W_out   = (const float*)d_in[7];
    float* out = (float*)d_out;

    // Workspace layout. logitsP (8 MB) aliases query_bf (dead after qv GEMM).
    char* ws = (char*)d_ws;
    ushort* W2T      = (ushort*)ws;                 ws += (size_t)NL * DD * 2;        // 0.5 MB
    ushort* WoutT    = (ushort*)ws;                 ws += (size_t)DD * DD * 2;        // 2 MB
    ushort* query_bf = (ushort*)ws;
    float*  logitsP  = (float*)ws;                  ws += (size_t)BT * DD * 2;        // 8 MB
    ushort* WqvT     = (ushort*)ws;                 ws += (size_t)2 * DD * DD * 2;    // 4 MB
    ushort* reluq    = (ushort*)ws;                 ws += (size_t)BT * DD * 2;        // 8 MB
    ushort* vbuf     = (ushort*)ws;                 ws += (size_t)BT * DD * 2;        // 8 MB
    ushort* xbuf     = (ushort*)ws;                 ws += (size_t)BT * DD * 2;        // 8 MB

    // 0) all conversions in one launch
    convert_all<<<R4, 256, 0, stream>>>(query, query_bf, W_qv, WqvT,
                                        W_out, WoutT, W2_0, W2_1, W2T);

    // 1) qv GEMM: [4096,1024]x[1024,2048] -> reluq bf16 + v bf16 (1024 blocks)
    gemm_db<2><<<dim3(32 * 32, 1), 256, 0, stream>>>(query_bf, WqvT, DD, DD,
                                                     nullptr, reluq, vbuf, 0);
    // 2) logits GEMM split-K=2: relu(q) x W2T -> logitsP (256 blocks)
    gemm_db<3><<<dim3(4 * 32, KSPLIT), 256, 0, stream>>>(reluq, W2T, DD, DD / KSPLIT,
                                                         logitsP, nullptr, nullptr, NL);
    // 3) softmax (+partial sum) + sliding window -> xbuf bf16
    attn_window_kernel<<<256, 256, 0, stream>>>(vbuf, logitsP, scale_w, xbuf);

    // 4) out GEMM: x x WoutT -> out f32 (512 blocks)
    gemm_db<0><<<dim3(16 * 32, 1), 256, 0, stream>>>(xbuf, WoutT, DD, DD,
                                                     out, nullptr, nullptr, DD);
}